// Round 5
// baseline (535.112 us; speedup 1.0000x reference)
//
#include <hip/hip_runtime.h>
#include <hip/hip_bf16.h>
#include <hip/hip_fp8.h>
#include <math.h>
#include <stdint.h>

typedef __hip_bfloat16 bf16;

#define NN 16384
#define EE 65536
#define BB 512

typedef __attribute__((ext_vector_type(8))) short short8;
typedef __attribute__((ext_vector_type(2))) short short2v;
typedef __attribute__((ext_vector_type(4))) float floatx4;
typedef __attribute__((ext_vector_type(2))) float floatx2;
typedef __attribute__((ext_vector_type(2))) unsigned int uint2v;

#define GKEY_NEGINF 0x007FFFFFu   // fkey(-inf)

__device__ __forceinline__ float lrelu_f(float x){ return x >= 0.f ? x : 0.01f*x; }

__device__ __forceinline__ float b2f(short s){
    unsigned int u = ((unsigned int)(unsigned short)s) << 16;
    float f; __builtin_memcpy(&f, &u, 4); return f;
}
__device__ __forceinline__ short f2b(float f){
    bf16 b = (bf16)f;
    short s; __builtin_memcpy(&s, &b, 2); return s;
}
// order-preserving float<->u32 for atomicMax pooling
__device__ __forceinline__ unsigned int fkey(float f){
    unsigned int u; __builtin_memcpy(&u, &f, 4);
    return (u & 0x80000000u) ? ~u : (u | 0x80000000u);
}
__device__ __forceinline__ float fdec(unsigned int k){
    if (k == GKEY_NEGINF) return 0.f;   // empty graph -> where(isfinite)=0
    unsigned int u = (k & 0x80000000u) ? (k ^ 0x80000000u) : ~k;
    float f; __builtin_memcpy(&f, &u, 4); return f;
}

// ================= MFMA bf16 GEMM: C[m,n] = A[m,:K] @ W[:,n] + bias[n] =================
// R5 structure: NO main-loop LDS, NO barriers. Both A and B fragments are loaded
// directly global->VGPR with a static 2-deep circular prefetch (rule #20: all indices
// compile-time via full unroll). The R1-R4 barrier-pair-per-K-step structure capped
// each K-step's wall at ~730cy vs ~160cy of MFMA (MfmaUtil 22%) -- the s_barrier
// convoy is structural (m97-ceiling). Removing it decouples waves; latency is hidden
// by PF=2 prefetch + TLP. A-frag reads are strided (16 rows x 16B per lane-group) but
// consume full 64B lines (4 chunks covered by the 4 lane-groups); the 2x redundancy
// between wave pairs hits L1 (per-K-step A slice = 8KB << 32KB L1).
// LDS kept ONLY for the once-per-block wave-private epilogue transpose.
template<int KSC>
__global__ __launch_bounds__(256)
void mfma_gemm(const bf16* __restrict__ A, int lda,
               const bf16* __restrict__ Bp,      // packed [nTile][KSC][64][8]
               const float* __restrict__ bias,
               bf16* __restrict__ C, int ldc,
               unsigned char* __restrict__ C2, int ldc2, int nsplit)
{
    __shared__ __align__(16) char smem[20480];
    bf16* epi = (bf16*)smem;            // epilogue only (wave-private 5KB regions)
    const int tid  = threadIdx.x;
    const int wave = tid >> 6;
    const int lane = tid & 63;
    const int wm = (wave & 1) * 64;
    const int wn = (wave >> 1) * 64;
    const int m0 = blockIdx.x * 128;
    const int n0 = blockIdx.y * 128;
    const bool isf8 = (n0 >= nsplit);
    const int ntile0 = (n0 + wn) >> 4;  // B-fragment tile base for this wave

    const int arow = lane & 15;
    const int aq   = (lane >> 4) * 8;
    // per-wave A fragment base: row m0+wm+arow, col-chunk aq
    const bf16* Aw = A + (size_t)(m0 + wm + arow)*lda + aq;
    const bf16* Bw = Bp + (size_t)ntile0*KSC*512 + lane*8;

    floatx4 acc[4][4];
    #pragma unroll
    for (int i=0;i<4;i++)
        #pragma unroll
        for (int j=0;j<4;j++) acc[i][j] = (floatx4){0.f,0.f,0.f,0.f};

    constexpr int PF = (KSC < 2) ? KSC : 2;   // prefetch depth (K-steps)
    short8 a_[PF][4], b_[PF][4];
    #pragma unroll
    for (int p=0; p<PF; p++){
        #pragma unroll
        for (int i=0;i<4;i++) a_[p][i] = *(const short8*)(Aw + (size_t)i*16*lda + p*32);
        #pragma unroll
        for (int j=0;j<4;j++) b_[p][j] = *(const short8*)(Bw + ((size_t)j*KSC + p)*512);
    }

    #pragma unroll
    for (int ks = 0; ks < KSC; ks++){
        constexpr int DUMMY = 0; (void)DUMMY;
        const int s = ks % PF;               // compile-time after unroll
        #pragma unroll
        for (int i=0;i<4;i++)
            #pragma unroll
            for (int j=0;j<4;j++)
                acc[i][j] = __builtin_amdgcn_mfma_f32_16x16x32_bf16(a_[s][i], b_[s][j], acc[i][j], 0,0,0);
        if (ks + PF < KSC){
            #pragma unroll
            for (int i=0;i<4;i++) a_[s][i] = *(const short8*)(Aw + (size_t)i*16*lda + (ks+PF)*32);
            #pragma unroll
            for (int j=0;j<4;j++) b_[s][j] = *(const short8*)(Bw + ((size_t)j*KSC + (ks+PF))*512);
        }
    }

    const int crow = (lane >> 4) * 4;
    const int ccol = lane & 15;
    const int erow = lane >> 2;
    const int ecol = (lane & 3) * 8;
    bf16* ep = epi + wave * (64*40);
    #pragma unroll
    for (int j2 = 0; j2 < 2; j2++){
        if (j2) __syncthreads();
        #pragma unroll
        for (int jj = 0; jj < 2; jj++){
            const int j = j2*2 + jj;
            const float bsv = bias[n0 + wn + j*16 + ccol];
            #pragma unroll
            for (int i = 0; i < 4; i++)
                #pragma unroll
                for (int r = 0; r < 4; r++)
                    ep[(i*16 + crow + r)*40 + jj*16 + ccol] = (bf16)(acc[i][j][r] + bsv);
        }
        __syncthreads();
        #pragma unroll
        for (int q = 0; q < 4; q++){
            const int rr = q*16 + erow;
            short8 vv = *(const short8*)(ep + rr*40 + ecol);
            if (!isf8){
                *(short8*)(C + (size_t)(m0 + wm + rr)*ldc + n0 + wn + j2*32 + ecol) = vv;
            } else {
                // HW fp8 pack: 4 ops per 8 values
                int d0 = 0, d1 = 0;
                d0 = __builtin_amdgcn_cvt_pk_fp8_f32(b2f(vv[0]), b2f(vv[1]), d0, false);
                d0 = __builtin_amdgcn_cvt_pk_fp8_f32(b2f(vv[2]), b2f(vv[3]), d0, true);
                d1 = __builtin_amdgcn_cvt_pk_fp8_f32(b2f(vv[4]), b2f(vv[5]), d1, false);
                d1 = __builtin_amdgcn_cvt_pk_fp8_f32(b2f(vv[6]), b2f(vv[7]), d1, true);
                uint2v ob; ob[0] = (unsigned int)d0; ob[1] = (unsigned int)d1;
                *(uint2v*)(C2 + (size_t)(m0 + wm + rr)*ldc2 + (n0 - nsplit) + wn + j2*32 + ecol) = ob;
            }
        }
    }
}

// ---- tail weights: MFMA B-fragment order [tile][ks][lane][8]. Offsets in Wtp arena ----
#define OG1 0         // wg1 1024x512: T=32 KS=32
#define OG2 524288    // wg2 512x128:  T=8  KS=16
#define OR1 589824    // wr1 954x512:  T=32 KS=30
#define OR2 1081344   // wr2 512x256:  T=16 KS=16
#define OR3 1212416   // wr3 256x128:  T=8  KS=8
#define OF1 1245184   // wf1 384x512:  T=32 KS=12
#define OF2 1441792   // wf2 512x256:  T=16 KS=16
#define TAILW_TOTAL 1572864

// ============ merged prep: W1p,b1c,W2p,b2c + Wtp + xa + gkey in ONE dispatch ==========
// Weight order both layers: s | q | k | v  (s stays bf16 in epilogue; q/k/v -> fp8)
// W1p/W2p are in MFMA B-fragment order [tile][KS][lane][8].
#define P_W1T 98304
#define P_B1C (P_W1T + 1024)
#define P_W2T (P_B1C + 1048576)
#define P_B2C (P_W2T + 4096)
#define P_WTP (P_B2C + TAILW_TOTAL)
#define P_XA  (P_WTP + 2*NN*96)
#define P_GK  (P_XA + 2*BB*1024)
__global__ void prep_mega_kernel(
    const float* __restrict__ wq1, const float* __restrict__ wk1,
    const float* __restrict__ wv1, const float* __restrict__ ws1,
    const float* __restrict__ bq1, const float* __restrict__ bk1,
    const float* __restrict__ bv1, const float* __restrict__ bs1,
    const float* __restrict__ wq2, const float* __restrict__ wk2,
    const float* __restrict__ wv2, const float* __restrict__ ws2,
    const float* __restrict__ bq2, const float* __restrict__ bk2,
    const float* __restrict__ bv2, const float* __restrict__ bs2v,
    const float* __restrict__ wg1, const float* __restrict__ wg2,
    const float* __restrict__ wr1, const float* __restrict__ wr2,
    const float* __restrict__ wr3, const float* __restrict__ wf1,
    const float* __restrict__ wf2,
    const float* __restrict__ x1,  const float* __restrict__ x2,
    bf16* __restrict__ W1t, float* __restrict__ b1c,
    bf16* __restrict__ W2t, float* __restrict__ b2c,
    bf16* __restrict__ Wtp, bf16* __restrict__ xa,
    unsigned int* __restrict__ gkey)
{
    int i = blockIdx.x*256 + threadIdx.x;
    if (i < P_W1T){                      // W1p: [64 tiles][3 ks][64][8], n order s|q|k|v
        int j  = i & 7;
        int ln = (i >> 3) & 63;
        int rest = i >> 9;               // 0..191
        int ks = rest % 3, tile = rest / 3;
        int n = tile*16 + (ln & 15);     // 0..1023
        int k = ks*32 + (ln >> 4)*8 + j; // 0..95
        int seg = n >> 8;
        const float* w = (seg==0)?ws1:(seg==1)?wq1:(seg==2)?wk1:wv1;
        W1t[i] = (k < 78) ? (bf16)w[(size_t)k*256 + (n & 255)] : (bf16)0.f;
        return;
    }
    if (i < P_B1C){                      // b1c (s|q|k|v)
        int n = i - P_W1T;
        int seg = n >> 8;
        const float* b = (seg==0)?bs1:(seg==1)?bq1:(seg==2)?bk1:bv1;
        b1c[n] = b[n & 255];
        return;
    }
    if (i < P_W2T){                      // W2p: [2 heads][128 tiles][8 ks][64][8]
        int loc = i - P_B1C;
        int h  = loc >> 19;
        int l2 = loc & 524287;
        int j  = l2 & 7;
        int ln = (l2 >> 3) & 63;
        int rest = l2 >> 9;              // 0..1023
        int ks = rest & 7, tile = rest >> 3;
        int n = tile*16 + (ln & 15);     // 0..2047 within head (s|q|k|v)
        int k = ks*32 + (ln >> 4)*8 + j; // 0..255
        const float* w = (n<512)?ws2:(n<1024)?wq2:(n<1536)?wk2:wv2;
        W2t[loc] = (bf16)w[(size_t)k*1024 + h*512 + (n & 511)];
        return;
    }
    if (i < P_B2C){                      // b2c (s|q|k|v)
        int loc = i - P_W2T;
        int j = loc & 2047, h = loc >> 11;
        const float* b = (j<512)?bs2v:(j<1024)?bq2:(j<1536)?bk2:bv2;
        b2c[loc] = b[h*512 + (j & 511)];
        return;
    }
    if (i < P_WTP){                      // packed tail weights, MFMA B-fragment order
        int t = i - P_B2C;
        const float* W; int N, K, KS, base;
        if      (t < OG2){ W = wg1; N = 512; K = 1024; KS = 32; base = OG1; }
        else if (t < OR1){ W = wg2; N = 128; K = 512;  KS = 16; base = OG2; }
        else if (t < OR2){ W = wr1; N = 512; K = 954;  KS = 30; base = OR1; }
        else if (t < OR3){ W = wr2; N = 256; K = 512;  KS = 16; base = OR2; }
        else if (t < OF1){ W = wr3; N = 128; K = 256;  KS = 8;  base = OR3; }
        else if (t < OF2){ W = wf1; N = 512; K = 384;  KS = 12; base = OF1; }
        else             { W = wf2; N = 256; K = 512;  KS = 16; base = OF2; }
        int loc = t - base;
        int j  = loc & 7;
        int ln = (loc >> 3) & 63;
        int rest = loc >> 9;
        int ks = rest % KS;
        int tile = rest / KS;
        int n = tile*16 + (ln & 15);
        int k = ks*32 + (ln >> 4)*8 + j;
        Wtp[t] = (k < K) ? (bf16)W[(size_t)k*N + n] : (bf16)0.f;
        return;
    }
    if (i < P_XA){                       // xa: [2NN][96] bf16 (zero-padded K)
        int t = i - P_WTP;
        int r = t / 96, c = t - r*96;
        const float* x = (r >= NN) ? x2 : x1;
        int lr = r & (NN-1);
        xa[t] = (c < 78) ? (bf16)x[(size_t)lr*78 + c] : (bf16)0.f;
        return;
    }
    if (i < P_GK){                       // gkey init
        gkey[i - P_XA] = GKEY_NEGINF;
    }
}

// ================= CSR build (both branches, stacked) =================
__global__ void hist_kernel(const int* __restrict__ ei1, const int* __restrict__ ei2,
                            int* __restrict__ cnt){
    int eg = blockIdx.x*256 + threadIdx.x;     // 0..2EE
    int br = eg >> 16, e = eg & (EE-1);
    const int* ei = br ? ei2 : ei1;
    atomicAdd(&cnt[br*NN + ei[EE + e]], 1);
}

__global__ __launch_bounds__(1024)
void scan_kernel(const int* __restrict__ hist, int* __restrict__ rowptr,
                 int* __restrict__ rowcur){
    const int br = blockIdx.x;
    hist   += br*NN;
    rowptr += br*(NN+1);
    rowcur += br*(NN+1);
    __shared__ int sums[1024];
    const int t = threadIdx.x;
    const int base = t*16;
    int loc[16]; int s = 0;
    #pragma unroll
    for (int i=0;i<16;i++){ loc[i]=s; s += hist[base+i]; }
    sums[t] = s; __syncthreads();
    for (int o=1;o<1024;o<<=1){
        int v = (t>=o) ? sums[t-o] : 0;
        __syncthreads();
        sums[t] += v;
        __syncthreads();
    }
    int pref = (t>0) ? sums[t-1] : 0;
    #pragma unroll
    for (int i=0;i<16;i++){
        int v = pref + loc[i];
        rowptr[base+i] = v;
        rowcur[base+i] = v;
    }
    if (t==1023) rowptr[NN] = sums[1023];
}

__global__ void scatter_kernel(const int* __restrict__ ei1, const int* __restrict__ ei2,
                               int* __restrict__ rowcur, int* __restrict__ srcs){
    int eg = blockIdx.x*256 + threadIdx.x;
    int br = eg >> 16, e = eg & (EE-1);
    const int* ei = br ? ei2 : ei1;
    int d = ei[EE + e];
    int pos = atomicAdd(&rowcur[br*(NN+1) + d], 1);
    srcs[br*EE + pos] = ei[e];
}

// ======= attention layer-1: s bf16 [2NN,256], q/k/v fp8 [2NN,768], H=2, D=128 =========
__global__ __launch_bounds__(256)
void attn128_f8(const bf16* __restrict__ s1, const unsigned char* __restrict__ f81,
                bf16* __restrict__ hout,
                const int* __restrict__ rowptr, const int* __restrict__ srcs)
{
    const int lane = threadIdx.x & 63;
    const int gw = blockIdx.x * 4 + (threadIdx.x >> 6);
    const int n = gw >> 1;               // global node 0..2NN
    const int h = gw & 1;
    int br = n >> 14;
    int brNN = br*NN, nl = n - brNN;
    rowptr += br*(NN+1); srcs += br*EE;
    const float qscale = rsqrtf(128.f) * 1.44269504f;
    const int hd = h*128 + lane*2;

    unsigned short qw; __builtin_memcpy(&qw, f81 + (size_t)n*768 + hd, 2);
    floatx2 qd = __builtin_amdgcn_cvt_pk_f32_fp8((int)qw, false);
    float qr[2] = { qd[0]*qscale, qd[1]*qscale };

    const int e0 = rowptr[nl], e1 = rowptr[nl+1];
    float m = -INFINITY, z = 0.f;
    float acc[2] = {0.f, 0.f};

    for (int base = e0; base < e1; base += 4){
        const int cnt = min(4, e1 - base);
        int sl = srcs[min(base + (lane & 3), e1 - 1)];
        int src[4];
        #pragma unroll
        for (int j=0;j<4;j++) src[j] = __shfl(sl, j, 64);

        unsigned short kw[4], vw[4];
        #pragma unroll
        for (int j=0;j<4;j++){
            if (j < cnt){
                const unsigned char* rp = f81 + (size_t)(brNN + src[j])*768;
                __builtin_memcpy(&kw[j], rp + 256 + hd, 2);
                __builtin_memcpy(&vw[j], rp + 512 + hd, 2);
            }
        }
        float dt[4];
        #pragma unroll
        for (int j=0;j<4;j++){
            float d = 0.f;
            if (j < cnt){
                floatx2 kd = __builtin_amdgcn_cvt_pk_f32_fp8((int)kw[j], false);
                d = qr[0]*kd[0] + qr[1]*kd[1];
            }
            dt[j] = d;
        }
        #pragma unroll
        for (int o=32;o;o>>=1){
            #pragma unroll
            for (int j=0;j<4;j++) dt[j] += __shfl_xor(dt[j], o, 64);
        }
        float cm = -INFINITY;
        #pragma unroll
        for (int j=0;j<4;j++) if (j < cnt) cm = fmaxf(cm, dt[j]);
        const float mn = fmaxf(m, cm);
        const float cs = exp2f(m - mn);
        z *= cs;
        acc[0] *= cs; acc[1] *= cs;
        #pragma unroll
        for (int j=0;j<4;j++){
            if (j < cnt){
                const float w = exp2f(dt[j] - mn);
                z += w;
                floatx2 vd = __builtin_amdgcn_cvt_pk_f32_fp8((int)vw[j], false);
                acc[0] += w*vd[0];
                acc[1] += w*vd[1];
            }
        }
        m = mn;
    }
    const float invz = 1.0f/(z + 1e-16f);
    const short2v sv = *(const short2v*)(s1 + (size_t)n*256 + hd);
    short2v ov;
    ov[0] = f2b(lrelu_f(b2f(sv[0]) + acc[0]*invz));
    ov[1] = f2b(lrelu_f(b2f(sv[1]) + acc[1]*invz));
    *(short2v*)(hout + (size_t)n*256 + hd) = ov;
}

// ====== attention layer-2 (stacked branches) + fused segment-max pool ================
// s bf16 [2NN,512]; q/k/v fp8 [2NN,1536] (q 0-511, k 512-1023, v 1024-1535).
__global__ __launch_bounds__(256)
void attn512_f8(const bf16* __restrict__ s2, const unsigned char* __restrict__ f82,
                const int* __restrict__ rowptr, const int* __restrict__ srcs,
                const int* __restrict__ bt1, const int* __restrict__ bt2,
                unsigned int* __restrict__ gkey, int gc0)
{
    __shared__ float Sh[4][512];
    __shared__ int Sgid[4];
    const int lane = threadIdx.x & 63;
    const int wave = threadIdx.x >> 6;
    const int n = blockIdx.x * 4 + wave;     // global node 0..2NN (block never spans br)
    const int br = n >> 14;
    const int brNN = br*NN, nl = n - brNN;
    const int* rp_ = rowptr + br*(NN+1);
    const int* sp_ = srcs + br*EE;
    const float qscale = rsqrtf(512.f) * 1.44269504f;
    const int hd = lane*8;

    float qr[8];
    {
        const uint2v qv = *(const uint2v*)(f82 + (size_t)n*1536 + hd);
        floatx2 a = __builtin_amdgcn_cvt_pk_f32_fp8((int)qv[0], false);
        floatx2 b = __builtin_amdgcn_cvt_pk_f32_fp8((int)qv[0], true);
        floatx2 c = __builtin_amdgcn_cvt_pk_f32_fp8((int)qv[1], false);
        floatx2 d = __builtin_amdgcn_cvt_pk_f32_fp8((int)qv[1], true);
        qr[0]=a[0]*qscale; qr[1]=a[1]*qscale; qr[2]=b[0]*qscale; qr[3]=b[1]*qscale;
        qr[4]=c[0]*qscale; qr[5]=c[1]*qscale; qr[6]=d[0]*qscale; qr[7]=d[1]*qscale;
    }

    const int e0 = rp_[nl], e1 = rp_[nl+1];
    float m = -INFINITY, z = 0.f;
    float acc[8];
    #pragma unroll
    for (int i=0;i<8;i++) acc[i] = 0.f;

    for (int base = e0; base < e1; base += 4){
        const int cnt = min(4, e1 - base);
        int sl = sp_[min(base + (lane & 3), e1 - 1)];
        int src[4];
        #pragma unroll
        for (int j=0;j<4;j++) src[j] = __shfl(sl, j, 64);

        uint2v k2[4], v2[4];
        #pragma unroll
        for (int j=0;j<4;j++){
            if (j < cnt){
                const unsigned char* rp = f82 + (size_t)(brNN + src[j])*1536;
                k2[j] = *(const uint2v*)(rp + 512 + hd);
                v2[j] = *(const uint2v*)(rp + 1024 + hd);
            }
        }
        float dt[4];
        #pragma unroll
        for (int j=0;j<4;j++){
            float d = 0.f;
            if (j < cnt){
                floatx2 p0 = __builtin_amdgcn_cvt_pk_f32_fp8((int)k2[j][0], false);
                floatx2 p1 = __builtin_amdgcn_cvt_pk_f32_fp8((int)k2[j][0], true);
                floatx2 p2 = __builtin_amdgcn_cvt_pk_f32_fp8((int)k2[j][1], false);
                floatx2 p3 = __builtin_amdgcn_cvt_pk_f32_fp8((int)k2[j][1], true);
                d = qr[0]*p0[0] + qr[1]*p0[1] + qr[2]*p1[0] + qr[3]*p1[1]
                  + qr[4]*p2[0] + qr[5]*p2[1] + qr[6]*p3[0] + qr[7]*p3[1];
            }
            dt[j] = d;
        }
        #pragma unroll
        for (int o=32;o;o>>=1){
            #pragma unroll
            for (int j=0;j<4;j++) dt[j] += __shfl_xor(dt[j], o, 64);
        }
        float cm = -INFINITY;
        #pragma unroll
        for (int j=0;j<4;j++) if (j < cnt) cm = fmaxf(cm, dt[j]);
        const float mn = fmaxf(m, cm);
        const float cs = exp2f(m - mn);
        z *= cs;
        #pragma unroll
        for (int i=0;i<8;i++) acc[i] *= cs;
        #pragma unroll
        for (int j=0;j<4;j++){
            if (j < cnt){
                const float w = exp2f(dt[j] - mn);
                z += w;
                floatx2 p0 = __builtin_amdgcn_cvt_pk_f32_fp8((int)v2[j][0], false);
                floatx2 p1 = __builtin_amdgcn_cvt_pk_f32_fp8((int)v2[j][0], true);
                floatx2 p2 = __builtin_amdgcn_cvt_pk_f32_fp8((int)v2[j][1], false);
                floatx2 p3 = __builtin_amdgcn_cvt_pk_f32_fp8((int)v2[j][1], true);
                acc[0] += w*p0[0]; acc[1] += w*p0[1]; acc[2] += w*p1[0]; acc[3] += w*p1[1];
                acc[4] += w*p2[0]; acc[5] += w*p2[1]; acc[6] += w*p3[0]; acc[7] += w*p3[1];
            }
        }
        m = mn;
    }
    const float invz = 1.0f/(z + 1e-16f);
    const short8 sv = *(const short8*)(s2 + (size_t)n*512 + hd);
    #pragma unroll
    for (int i=0;i<8;i++) Sh[wave][hd + i] = lrelu_f(b2f(sv[i]) + acc[i]*invz);
    if (lane == 0) Sgid[wave] = br*BB + (br ? bt2[nl] : bt1[nl]);
    __syncthreads();

    // segmented max over the block's 4 rows, one atomic per (graph,col) run
    #pragma unroll
    for (int cc=0; cc<2; cc++){
        const int col = threadIdx.x*2 + cc;
        float mx = Sh[0][col];
        int gid = Sgid[0];
        #pragma unroll
        for (int r=1; r<4; r++){
            if (Sgid[r] == gid) mx = fmaxf(mx, Sh[r][col]);
            else {
                atomicMax(&gkey[(size_t)gid*1024 + gc0 + col], fkey(mx));
                gid = Sgid[r]; mx = Sh[r][col];
            }
        }
        atomicMax(&gkey[(size_t)gid*1024 + gc0 + col], fkey(mx));
    }
}

// ================= tail dense layer via MFMA (1024 threads = 16 waves) ===============
// K is COMPILE-TIME: KS constexpr, ks-loop fully unrolled, with an explicit 8-deep
// circular B-prefetch (statically indexed -> stays in VGPRs, rule #20).
// lda/ldc are PADDED strides (+4 floats) -> bank-conflict-free (R3, verified 512 cnt).
template<int R, int N, int K, int ACT>
__device__ __forceinline__ void dense_mfma(
    const bf16* __restrict__ Wm, const float* __restrict__ bias,
    const float* __restrict__ gam, const float* __restrict__ bet, float bns,
    const float* A, int lda, float* C, int ldc, int tid)
{
    constexpr int T   = N / 16;
    constexpr int TPW = (T + 15) / 16;
    constexpr int KS  = ((K + 31) & ~31) >> 5;
    constexpr int PF  = (KS < 8) ? KS : 8;       // B-prefetch depth (ks-steps)
    const int wave = tid >> 6;
    const int lane = tid & 63;
    const int am = lane & 15;
    const int ak = (lane >> 4) * 8;

    floatx4 acc[TPW];
    #pragma unroll
    for (int tp=0; tp<TPW; tp++) acc[tp] = (floatx4){0.f,0.f,0.f,0.f};

    short8 bb[PF][TPW];
    #pragma unroll
    for (int p=0; p<PF; p++){
        #pragma unroll
        for (int tp=0; tp<TPW; tp++){
            const int tile = wave + tp*16;
            if (tile < T)
                bb[p][tp] = *(const short8*)(Wm + ((size_t)(tile*KS + p))*512 + lane*8);
        }
    }

    #pragma unroll
    for (int ks = 0; ks < KS; ks++){
        short8 af = (short8){0,0,0,0,0,0,0,0};
        if (am < R){
            const float* ap = A + am*lda + ks*32 + ak;
            const floatx4 a0 = *(const floatx4*)ap;
            const floatx4 a1 = *(const floatx4*)(ap + 4);
            af[0]=f2b(a0[0]); af[1]=f2b(a0[1]); af[2]=f2b(a0[2]); af[3]=f2b(a0[3]);
            af[4]=f2b(a1[0]); af[5]=f2b(a1[1]); af[6]=f2b(a1[2]); af[7]=f2b(a1[3]);
        }
        #pragma unroll
        for (int tp=0; tp<TPW; tp++){
            const int tile = wave + tp*16;
            if (tile < T)
                acc[tp] = __builtin_amdgcn_mfma_f32_16x16x32_bf16(af, bb[ks % PF][tp], acc[tp], 0,0,0);
        }
        if (ks + PF < KS){
            #pragma unroll
            for (int tp=0; tp<TPW; tp++){
                const int tile = wave + tp*16;
                if (tile < T)
                    bb[ks % PF][tp] = *(const short8*)(Wm + ((size_t)(tile*KS + ks + PF))*512 + lane*8);
            }
        }
    }
    const int crow = (lane >> 4) * 4;
    const int ccol = lane & 15;
    #pragma unroll
    for (int tp=0; tp<TPW; tp++){
        const int tile = wave + tp*16;
        if (tile < T){
            #pragma unroll
            for (int r=0; r<4; r++){
                const int row = crow + r;
                if (row < R){
                    const int n = tile*16 + ccol;
                    float v = acc[tp][r] + bias[n];
                    if (ACT==1) v = lrelu_f(v);
                    if (ACT==2) v = lrelu_f(v*bns*gam[n] + bet[n]);
                    C[row*ldc + n] = v;
                }
            }
        }
    }
    __syncthreads();
}

// ================= fused tail: graph-head + cell branch + head MLP, 2 graphs/block ====
// All activation buffers padded +4 floats/row (16B) -> bank-conflict-free dense_mfma.
__global__ __launch_bounds__(1024)
void tail_kernel(const unsigned int* __restrict__ gkey,  // [2*BB][1024] encoded maxes
                 const float* __restrict__ cell,         // [BB][954]
                 const bf16*  __restrict__ Wtp,          // packed tail weights
                 const float* __restrict__ bg1, const float* __restrict__ bg2,
                 const float* __restrict__ br1, const float* __restrict__ br2,
                 const float* __restrict__ br3,
                 const float* __restrict__ bf1,
                 const float* __restrict__ gbn1, const float* __restrict__ bbn1,
                 const float* __restrict__ bf2,
                 const float* __restrict__ gbn2, const float* __restrict__ bbn2,
                 const float* __restrict__ wf3, const float* __restrict__ bf3,
                 float bns, float* __restrict__ outp)
{
    __shared__ float Sg[4][1028];    // rows: lg*2 + br   (pad +4)
    __shared__ float Sgh[4][516];
    __shared__ float Sgout[4][132];
    __shared__ float Scell[2][964];
    __shared__ float Sc1[2][516];
    __shared__ float Sc2[2][260];
    __shared__ float Sc3[2][132];
    __shared__ float Sxc[2][388];
    __shared__ float Sf1[2][516];
    __shared__ float Sf2[2][260];
    __shared__ float inv4[4], invc[2], invx[2];

    const int tid = threadIdx.x;
    const int wv  = tid >> 6;
    const int ln  = tid & 63;
    const int b0  = blockIdx.x * 2;

    {
        int idx = tid*4;                 // 0..4092
        int r = idx >> 10, c = idx & 1023;
        int lg = r >> 1, br = r & 1;
        const unsigned int* gp = gkey + (size_t)(br*BB + b0 + lg)*1024 + c;
        #pragma unroll
        for (int i=0;i<4;i++) Sg[r][c+i] = fdec(gp[i]);
    }
    for (int idx = tid; idx < 2*954; idx += 1024){
        int r = (idx >= 954) ? 1 : 0;
        int c = idx - r*954;
        Scell[r][c] = cell[(size_t)(b0 + r)*954 + c];
    }
    if (tid < 12){ int r = tid/6; Scell[r][954 + tid%6] = 0.f; }
    __syncthreads();

    if (wv < 2){
        float s = 0.f;
        for (int c = ln; c < 954; c += 64){ float v = Scell[wv][c]; s += v*v; }
        #pragma unroll
        for (int o=32;o;o>>=1) s += __shfl_xor(s, o, 64);
        if (ln == 0) invc[wv] = 1.0f / fmaxf(sqrtf(s), 1e-12f);
    }
    __syncthreads();
    #pragma unroll
    for (int r=0;r<2;r++)
        for (int c = tid; c < 954; c += 1024) Scell[r][c] *= invc[r];
    __syncthreads();

    dense_mfma<4,512,1024,1>(Wtp+OG1, bg1, nullptr, nullptr, 1.f, &Sg[0][0],   1028, &Sgh[0][0],  516, tid);
    dense_mfma<4,128,512,0>(Wtp+OG2, bg2, nullptr, nullptr, 1.f, &Sgh[0][0],  516,  &Sgout[0][0],132, tid);
    dense_mfma<2,512,954,1>(Wtp+OR1, br1, nullptr, nullptr, 1.f, &Scell[0][0], 964, &Sc1[0][0],  516, tid);
    dense_mfma<2,256,512,1>(Wtp+OR2, br2, nullptr, nullptr, 1.f, &Sc1[0][0],   516, &Sc2[0][0],  260, tid);
    dense_mfma<2,128,256,0>(Wtp+OR3, br3, nullptr, nullptr, 1.f, &Sc2[0][0],   260, &Sc3[0][0],  132, tid);

    if (wv < 4){
        float a = Sgout[wv][ln], bq = Sgout[wv][ln+64];
        float s = a*a + bq*bq;
        #pragma unroll
        for (int o=32;o;o>>=1) s += __shfl_xor(s, o, 64);
        if (ln == 0) inv4[wv] = 1.0f / fmaxf(sqrtf(s), 1e-12f);
    }
    __syncthreads();

    if (tid < 768){
        int lg = tid / 384, j = tid - lg*384;
        float v;
        if (j < 128)      v = Sgout[lg*2+0][j]     * inv4[lg*2+0];
        else if (j < 256) v = Sgout[lg*2+1][j-128] * inv4[lg*2+1];
        else              v = Sc3[lg][j-256];
        Sxc[lg][j] = v;
    }
    __syncthreads();
    if (wv < 2){
        float s = 0.f;
        #pragma unroll
        for (int i=0;i<6;i++){ float v = Sxc[wv][ln + i*64]; s += v*v; }
        #pragma unroll
        for (int o=32;o;o>>=1) s += __shfl_xor(s, o, 64);
        if (ln == 0) invx[wv] = 1.0f / fmaxf(sqrtf(s), 1e-12f);
    }
    __syncthreads();
    if (tid < 768){
        int lg = tid / 384, j = tid - lg*384;
        Sxc[lg][j] *= invx[lg];
    }
    __syncthreads();

    dense_mfma<2,512,384,2>(Wtp+OF1, bf1, gbn1, bbn1, bns, &Sxc[0][0], 388, &Sf1[0][0], 516, tid);
    dense_mfma<2,256,512,2>(Wtp+OF2, bf2, gbn2, bbn2, bns, &Sf1[0][0], 516, &Sf2[0][0], 260, tid);

    if (wv < 2){
        float s = 0.f;
        #pragma unroll
        for (int i=0;i<4;i++){ int c = ln + i*64; s += Sf2[wv][c]*wf3[c]; }
        #pragma unroll
        for (int o=32;o;o>>=1) s += __shfl_xor(s, o, 64);
        if (ln == 0) outp[b0 + wv] = 1.0f/(1.0f + expf(-(s + bf3[0])));
    }
}

extern "C" void kernel_launch(void* const* d_in, const int* in_sizes, int n_in,
                              void* d_out, int out_size, void* d_ws, size_t ws_size,
                              hipStream_t stream)
{
    const float* x1  = (const float*)d_in[0];
    const int*   ei1 = (const int*)  d_in[1];
    const int*   bt1 = (const int*)  d_in[2];
    const float* x2  = (const float*)d_in[3];
    const int*   ei2 = (const int*)  d_in[4];
    const int*   bt2 = (const int*)  d_in[5];
    const float* cell= (const float*)d_in[6];
    const float* wq1=(const float*)d_in[7];  const float* bq1=(const float*)d_in[8];
    const float* wk1=(const float*)d_in[9];  const float* bk1=(const float*)d_in[10];
    const float* wv1=(const float*)d_in[11]; const float* bv1=(const float*)d_in[12];
    const float* ws1=(const float*)d_in[13]; const float* bs1=(const float*)d_in[14];
    const float* wq2=(const float*)d_in[15]; const float* bq2=(const float*)d_in[16];
    const float* wk2=(const float*)d_in[17]; const float* bk2=(const float*)d_in[18];
    const float* wv2=(const float*)d_in[19]; const float* bv2=(const float*)d_in[20];
    const float* ws2=(const float*)d_in[21]; const float* bs2q=(const float*)d_in[22];
    const float* wg1=(const float*)d_in[23]; const float* bg1=(const float*)d_in[24];
    const float* wg2=(const float*)d_in[25]; const float* bg2=(const float*)d_in[26];
    const float* wr1=(const float*)d_in[27]; const float* br1=(const float*)d_in[28];
    const float* wr2=(const float*)d_in[29]; const float* br2=(const float*)d_in[30];
    const float* wr3=(const float*)d_in[31]; const float* br3=(const float*)d_in[32];
    const float* wf1=(const float*)d_in[33]; const float* bf1=(const float*)d_in[34];
    const float* gbn1=(const float*)d_in[35];const float* bbn1=(const float*)d_in[36];
    const float* wf2=(const float*)d_in[37]; const float* bf2=(const float*)d_in[38];
    const float* gbn2=(const float*)d_in[39];const float* bbn2=(const float*)d_in[40];
    const float* wf3=(const float*)d_in[41]; const float* bf3=(const float*)d_in[42];
    float* outp = (float*)d_out;
    (void)in_sizes; (void)n_in; (void)out_size; (void)ws_size;

    const float BNS = 1.0f / sqrtf(1.0f + 1e-5f);

    // ---- workspace arena (~107 MB peak; BIG region phase-aliased) ----
    char* basep = (char*)d_ws;
    size_t off = 0;
    auto alloc = [&](size_t nbytes)->char* {
        char* p = basep + off;
        off += (nbytes + 255) & ~(size_t)255;
        return p;
    };
    int* rowptr2  = (int*)  alloc((size_t)2*(NN+1)*4);
    int* rowcur2  = (int*)  alloc((size_t)2*(NN+1)*4);
    int* cnt2     = (int*)  alloc((size_t)2*NN*4);
    int* srcs2    = (int*)  alloc((size_t)2*EE*4);
    unsigned int* gkey = (unsigned int*)alloc((size_t)2*BB*1024*4);  // pooled-max keys
    float* b1c    = (float*)alloc((size_t)1024*4);
    float* b2c    = (float*)alloc((size_t)4096*4);
    bf16* W1t     = (bf16*) alloc((size_t)1024*96*2);
    bf16* W2t     = (bf16*) alloc((size_t)2*2048*256*2);
    bf16* Wtp     = (bf16*) alloc((size_t)TAILW_TOTAL*2);
    bf16* h1      = (bf16*) alloc((size_t)2*NN*256*2);    // layer-1 out, both branches
    // BIG phase-aliased region (80 MB):
    //   phase1: xa [2NN,96] bf16 (6.3MB) | s1 [2NN,256] bf16 (16MB) | f81 [2NN,768] u8 (24MB)
    //   phase2: s2 [2NN,512] bf16 (32MB) | f82 [2NN,1536] u8 (48MB)
    char* BIG     = alloc((size_t)2*NN*512*2 + (size_t)2*NN*1536);
    bf16* xa      = (bf16*)BIG;
    bf16* s1a     = (bf16*)(BIG + 6291456);
    unsigned char* f81 = (unsigned char*)(BIG + 6291456 + 16777216);
    bf16* s2a     = (bf16*)BIG;
    unsigned char* f82 = (unsigned char*)(BIG + (size_t)2*NN*512*2);

    // ---- prep (1 mega dispatch) + CSR ----
    (void)hipMemsetAsync(cnt2, 0, (size_t)2*NN*4, stream);
    prep_mega_kernel<<<P_GK/256,256,0,stream>>>(
        wq1,wk1,wv1,ws1, bq1,bk1,bv1,bs1,
        wq2,wk2,wv2,ws2, bq2,bk2,bv2,bs2q,
        wg1,wg2,wr1,wr2,wr3,wf1,wf2,
        x1,x2,
        W1t,b1c,W2t,b2c, Wtp, xa, gkey);
    hist_kernel<<<2*EE/256,256,0,stream>>>(ei1, ei2, cnt2);
    scan_kernel<<<2,1024,0,stream>>>(cnt2, rowptr2, rowcur2);
    scatter_kernel<<<2*EE/256,256,0,stream>>>(ei1, ei2, rowcur2, srcs2);

    // ---- layer 1 (both branches stacked): [2NN,96]x[96,1024], s bf16 / q,k,v fp8 ----
    mfma_gemm<3><<<dim3(2*NN/128, 8),256,0,stream>>>(xa,96, W1t, b1c,
                                                     s1a,256, f81,768, 256);
    attn128_f8<<<2*NN*2/4,256,0,stream>>>(s1a, f81, h1, rowptr2, srcs2);

    // ---- layer 2 (branches stacked): per head GEMM + attn+pool fused ----
    for (int h=0; h<2; h++){
        mfma_gemm<8><<<dim3(2*NN/128, 16),256,0,stream>>>(
            h1, 256, W2t + (size_t)h*524288,
            b2c + h*2048, s2a,512, f82,1536, 512);
        attn512_f8<<<2*NN/4,256,0,stream>>>(s2a, f82, rowptr2, srcs2, bt1, bt2,
                                            gkey, h*512);
    }

    // ---- fused tail: graph-head + cell + head MLP + sigmoid, one dispatch ----
    tail_kernel<<<BB/2,1024,0,stream>>>(gkey, cell, Wtp,
                                        bg1,bg2, br1,br2,br3,
                                        bf1,gbn1,bbn1, bf2,gbn2,bbn2, wf3,bf3,
                                        BNS, outp);
}

// Round 6
// 457.860 us; speedup vs baseline: 1.1687x; 1.1687x over previous
//
#include <hip/hip_runtime.h>
#include <hip/hip_bf16.h>
#include <hip/hip_fp8.h>
#include <math.h>
#include <stdint.h>

typedef __hip_bfloat16 bf16;

#define NN 16384
#define EE 65536
#define BB 512

typedef __attribute__((ext_vector_type(8))) short short8;
typedef __attribute__((ext_vector_type(2))) short short2v;
typedef __attribute__((ext_vector_type(4))) float floatx4;
typedef __attribute__((ext_vector_type(2))) float floatx2;
typedef __attribute__((ext_vector_type(2))) unsigned int uint2v;

#define GKEY_NEGINF 0x007FFFFFu   // fkey(-inf)

__device__ __forceinline__ float lrelu_f(float x){ return x >= 0.f ? x : 0.01f*x; }

__device__ __forceinline__ float b2f(short s){
    unsigned int u = ((unsigned int)(unsigned short)s) << 16;
    float f; __builtin_memcpy(&f, &u, 4); return f;
}
__device__ __forceinline__ short f2b(float f){
    bf16 b = (bf16)f;
    short s; __builtin_memcpy(&s, &b, 2); return s;
}
// order-preserving float<->u32 for atomicMax pooling
__device__ __forceinline__ unsigned int fkey(float f){
    unsigned int u; __builtin_memcpy(&u, &f, 4);
    return (u & 0x80000000u) ? ~u : (u | 0x80000000u);
}
__device__ __forceinline__ float fdec(unsigned int k){
    if (k == GKEY_NEGINF) return 0.f;   // empty graph -> where(isfinite)=0
    unsigned int u = (k & 0x80000000u) ? (k ^ 0x80000000u) : ~k;
    float f; __builtin_memcpy(&f, &u, 4); return f;
}

// async 16B global->LDS. LDS dest is wave-uniform base; lane i lands at base+16*i.
__device__ __forceinline__ void gl2lds16(const void* g, void* l){
    __builtin_amdgcn_global_load_lds(
        (__attribute__((address_space(1))) unsigned int*)(uintptr_t)g,
        (__attribute__((address_space(3))) unsigned int*)(uintptr_t)l, 16, 0, 0);
}

// ================= MFMA bf16 GEMM: C[m,n] = A[m,:K] @ W[:,n] + bias[n] =================
// R6: R4 structure (LDS A-staging + barriers; B direct to VGPR) with the pipeline
// DEEPENED: 3 LDS A-buffers, staging issued 2 K-steps ahead, counted vmcnt(12)
// (= 6 ops/step x 2 newer steps in flight; tail steps 6 -> 0). R5 showed removing
// LDS+barriers is a regression (latency-bound, +25% FETCH); R4's 1-step-ahead
// staging exposed (latency - step_time) per step -> MfmaUtil 22%. 2-ahead doubles
// the latency budget. B uses a 3-deep static register rotation (indices are
// compile-time after full unroll, rule #20). Numerics identical to R4.
// A-tile keeps the 16B XOR swizzle (both sides: pre-swizzled global source + read).
template<int KSC>
__global__ __launch_bounds__(256)
void mfma_gemm(const bf16* __restrict__ A, int lda,
               const bf16* __restrict__ Bp,      // packed [nTile][KSC][64][8]
               const float* __restrict__ bias,
               bf16* __restrict__ C, int ldc,
               unsigned char* __restrict__ C2, int ldc2, int nsplit)
{
    __shared__ __align__(16) char smem[24576];
    bf16* As0 = (bf16*)smem;            // [128*32] buffer 0
    bf16* As1 = (bf16*)(smem + 8192);   // buffer 1
    bf16* As2 = (bf16*)(smem + 16384);  // buffer 2
    bf16* epi = (bf16*)smem;            // [4*64*40] epilogue (aliases buffers)
    const int tid  = threadIdx.x;
    const int wave = tid >> 6;
    const int lane = tid & 63;
    const int wm = (wave & 1) * 64;
    const int wn = (wave >> 1) * 64;
    const int m0 = blockIdx.x * 128;
    const int n0 = blockIdx.y * 128;
    const bool isf8 = (n0 >= nsplit);
    const int ntile0 = (n0 + wn) >> 4;  // B-fragment tile base for this wave

    const int srow = lane >> 2;
    // swizzled source column: physical chunk (lane&3) holds logical chunk (lane&3)^s(row)
    const int scol = (((lane & 3) ^ ((srow >> 1) & 3))) * 8;
    const int arow = lane & 15;
    // swizzled fragment read: logical chunk (lane>>4) -> physical chunk ^ s(row)
    const int aq   = (((lane >> 4) ^ ((arow >> 1) & 3))) * 8;

    floatx4 acc[4][4];
    #pragma unroll
    for (int i=0;i<4;i++)
        #pragma unroll
        for (int j=0;j<4;j++) acc[i][j] = (floatx4){0.f,0.f,0.f,0.f};

    auto bufsel = [&](int idx)->bf16* {
        const int s = idx % 3;
        return (s == 0) ? As0 : (s == 1) ? As1 : As2;
    };
    auto stageA = [&](int t){
        bf16* buf = bufsel(t);
        const int k0 = t*32;
        #pragma unroll
        for (int i = 0; i < 2; i++) {
            const int chunk = wave*2 + i;
            const int r = chunk*16 + srow;
            gl2lds16(A + (size_t)(m0 + r)*lda + k0 + scol, buf + chunk*512);
        }
    };

    short8 b_[3][4];
    auto loadB = [&](int slot, int ks){
        #pragma unroll
        for (int j=0;j<4;j++)
            b_[slot][j] = *(const short8*)(Bp + ((size_t)((ntile0 + j)*KSC + ks))*512 + lane*8);
    };

    // prologue: issue steps 0 and 1 (order: loadB then stageA, per-step)
    loadB(0, 0);
    stageA(0);
    if (KSC > 1){ loadB(1, 1); stageA(1); }

    #pragma unroll
    for (int t = 0; t < KSC; t++){
        if (t + 2 < KSC){
            loadB((t+2) % 3, t+2);            // 4 loads
            stageA(t+2);                      // 2 gl2lds
            // newest in flight: ops for steps t+1,t+2 = 12 -> step t's ops retired
            asm volatile("s_waitcnt vmcnt(12)" ::: "memory");
        } else if (t + 1 < KSC){
            asm volatile("s_waitcnt vmcnt(6)" ::: "memory");
        } else {
            asm volatile("s_waitcnt vmcnt(0)" ::: "memory");
        }
        __builtin_amdgcn_s_barrier();         // all waves' step-t stage visible
        __builtin_amdgcn_sched_barrier(0);    // don't hoist ds_reads above barrier
        bf16* cur = bufsel(t);
        short8 af[4];
        #pragma unroll
        for (int i=0;i<4;i++) af[i] = *(const short8*)(cur + (wm + i*16 + arow)*32 + aq);
        #pragma unroll
        for (int i=0;i<4;i++)
            #pragma unroll
            for (int j=0;j<4;j++)
                acc[i][j] = __builtin_amdgcn_mfma_f32_16x16x32_bf16(af[i], b_[t % 3][j], acc[i][j], 0,0,0);
        __builtin_amdgcn_sched_barrier(0);    // don't sink reads past barrier
        __builtin_amdgcn_s_barrier();         // reads done before overwrite of buf (t+3)
    }

    const int crow = (lane >> 4) * 4;
    const int ccol = lane & 15;
    const int erow = lane >> 2;
    const int ecol = (lane & 3) * 8;
    bf16* ep = epi + wave * (64*40);
    #pragma unroll
    for (int j2 = 0; j2 < 2; j2++){
        if (j2) __syncthreads();
        #pragma unroll
        for (int jj = 0; jj < 2; jj++){
            const int j = j2*2 + jj;
            const float bsv = bias[n0 + wn + j*16 + ccol];
            #pragma unroll
            for (int i = 0; i < 4; i++)
                #pragma unroll
                for (int r = 0; r < 4; r++)
                    ep[(i*16 + crow + r)*40 + jj*16 + ccol] = (bf16)(acc[i][j][r] + bsv);
        }
        __syncthreads();
        #pragma unroll
        for (int q = 0; q < 4; q++){
            const int rr = q*16 + erow;
            short8 vv = *(const short8*)(ep + rr*40 + ecol);
            if (!isf8){
                *(short8*)(C + (size_t)(m0 + wm + rr)*ldc + n0 + wn + j2*32 + ecol) = vv;
            } else {
                // HW fp8 pack: 4 ops per 8 values
                int d0 = 0, d1 = 0;
                d0 = __builtin_amdgcn_cvt_pk_fp8_f32(b2f(vv[0]), b2f(vv[1]), d0, false);
                d0 = __builtin_amdgcn_cvt_pk_fp8_f32(b2f(vv[2]), b2f(vv[3]), d0, true);
                d1 = __builtin_amdgcn_cvt_pk_fp8_f32(b2f(vv[4]), b2f(vv[5]), d1, false);
                d1 = __builtin_amdgcn_cvt_pk_fp8_f32(b2f(vv[6]), b2f(vv[7]), d1, true);
                uint2v ob; ob[0] = (unsigned int)d0; ob[1] = (unsigned int)d1;
                *(uint2v*)(C2 + (size_t)(m0 + wm + rr)*ldc2 + (n0 - nsplit) + wn + j2*32 + ecol) = ob;
            }
        }
    }
}

// ---- tail weights: MFMA B-fragment order [tile][ks][lane][8]. Offsets in Wtp arena ----
#define OG1 0         // wg1 1024x512: T=32 KS=32
#define OG2 524288    // wg2 512x128:  T=8  KS=16
#define OR1 589824    // wr1 954x512:  T=32 KS=30
#define OR2 1081344   // wr2 512x256:  T=16 KS=16
#define OR3 1212416   // wr3 256x128:  T=8  KS=8
#define OF1 1245184   // wf1 384x512:  T=32 KS=12
#define OF2 1441792   // wf2 512x256:  T=16 KS=16
#define TAILW_TOTAL 1572864

// ============ merged prep: W1p,b1c,W2p,b2c + Wtp + xa + gkey in ONE dispatch ==========
// Weight order both layers: s | q | k | v  (s stays bf16 in epilogue; q/k/v -> fp8)
// W1p/W2p are in MFMA B-fragment order [tile][KS][lane][8].
#define P_W1T 98304
#define P_B1C (P_W1T + 1024)
#define P_W2T (P_B1C + 1048576)
#define P_B2C (P_W2T + 4096)
#define P_WTP (P_B2C + TAILW_TOTAL)
#define P_XA  (P_WTP + 2*NN*96)
#define P_GK  (P_XA + 2*BB*1024)
__global__ void prep_mega_kernel(
    const float* __restrict__ wq1, const float* __restrict__ wk1,
    const float* __restrict__ wv1, const float* __restrict__ ws1,
    const float* __restrict__ bq1, const float* __restrict__ bk1,
    const float* __restrict__ bv1, const float* __restrict__ bs1,
    const float* __restrict__ wq2, const float* __restrict__ wk2,
    const float* __restrict__ wv2, const float* __restrict__ ws2,
    const float* __restrict__ bq2, const float* __restrict__ bk2,
    const float* __restrict__ bv2, const float* __restrict__ bs2v,
    const float* __restrict__ wg1, const float* __restrict__ wg2,
    const float* __restrict__ wr1, const float* __restrict__ wr2,
    const float* __restrict__ wr3, const float* __restrict__ wf1,
    const float* __restrict__ wf2,
    const float* __restrict__ x1,  const float* __restrict__ x2,
    bf16* __restrict__ W1t, float* __restrict__ b1c,
    bf16* __restrict__ W2t, float* __restrict__ b2c,
    bf16* __restrict__ Wtp, bf16* __restrict__ xa,
    unsigned int* __restrict__ gkey)
{
    int i = blockIdx.x*256 + threadIdx.x;
    if (i < P_W1T){                      // W1p: [64 tiles][3 ks][64][8], n order s|q|k|v
        int j  = i & 7;
        int ln = (i >> 3) & 63;
        int rest = i >> 9;               // 0..191
        int ks = rest % 3, tile = rest / 3;
        int n = tile*16 + (ln & 15);     // 0..1023
        int k = ks*32 + (ln >> 4)*8 + j; // 0..95
        int seg = n >> 8;
        const float* w = (seg==0)?ws1:(seg==1)?wq1:(seg==2)?wk1:wv1;
        W1t[i] = (k < 78) ? (bf16)w[(size_t)k*256 + (n & 255)] : (bf16)0.f;
        return;
    }
    if (i < P_B1C){                      // b1c (s|q|k|v)
        int n = i - P_W1T;
        int seg = n >> 8;
        const float* b = (seg==0)?bs1:(seg==1)?bq1:(seg==2)?bk1:bv1;
        b1c[n] = b[n & 255];
        return;
    }
    if (i < P_W2T){                      // W2p: [2 heads][128 tiles][8 ks][64][8]
        int loc = i - P_B1C;
        int h  = loc >> 19;
        int l2 = loc & 524287;
        int j  = l2 & 7;
        int ln = (l2 >> 3) & 63;
        int rest = l2 >> 9;              // 0..1023
        int ks = rest & 7, tile = rest >> 3;
        int n = tile*16 + (ln & 15);     // 0..2047 within head (s|q|k|v)
        int k = ks*32 + (ln >> 4)*8 + j; // 0..255
        const float* w = (n<512)?ws2:(n<1024)?wq2:(n<1536)?wk2:wv2;
        W2t[loc] = (bf16)w[(size_t)k*1024 + h*512 + (n & 511)];
        return;
    }
    if (i < P_B2C){                      // b2c (s|q|k|v)
        int loc = i - P_W2T;
        int j = loc & 2047, h = loc >> 11;
        const float* b = (j<512)?bs2v:(j<1024)?bq2:(j<1536)?bk2:bv2;
        b2c[loc] = b[h*512 + (j & 511)];
        return;
    }
    if (i < P_WTP){                      // packed tail weights, MFMA B-fragment order
        int t = i - P_B2C;
        const float* W; int N, K, KS, base;
        if      (t < OG2){ W = wg1; N = 512; K = 1024; KS = 32; base = OG1; }
        else if (t < OR1){ W = wg2; N = 128; K = 512;  KS = 16; base = OG2; }
        else if (t < OR2){ W = wr1; N = 512; K = 954;  KS = 30; base = OR1; }
        else if (t < OR3){ W = wr2; N = 256; K = 512;  KS = 16; base = OR2; }
        else if (t < OF1){ W = wr3; N = 128; K = 256;  KS = 8;  base = OR3; }
        else if (t < OF2){ W = wf1; N = 512; K = 384;  KS = 12; base = OF1; }
        else             { W = wf2; N = 256; K = 512;  KS = 16; base = OF2; }
        int loc = t - base;
        int j  = loc & 7;
        int ln = (loc >> 3) & 63;
        int rest = loc >> 9;
        int ks = rest % KS;
        int tile = rest / KS;
        int n = tile*16 + (ln & 15);
        int k = ks*32 + (ln >> 4)*8 + j;
        Wtp[t] = (k < K) ? (bf16)W[(size_t)k*N + n] : (bf16)0.f;
        return;
    }
    if (i < P_XA){                       // xa: [2NN][96] bf16 (zero-padded K)
        int t = i - P_WTP;
        int r = t / 96, c = t - r*96;
        const float* x = (r >= NN) ? x2 : x1;
        int lr = r & (NN-1);
        xa[t] = (c < 78) ? (bf16)x[(size_t)lr*78 + c] : (bf16)0.f;
        return;
    }
    if (i < P_GK){                       // gkey init
        gkey[i - P_XA] = GKEY_NEGINF;
    }
}

// ================= CSR build (both branches, stacked) =================
__global__ void hist_kernel(const int* __restrict__ ei1, const int* __restrict__ ei2,
                            int* __restrict__ cnt){
    int eg = blockIdx.x*256 + threadIdx.x;     // 0..2EE
    int br = eg >> 16, e = eg & (EE-1);
    const int* ei = br ? ei2 : ei1;
    atomicAdd(&cnt[br*NN + ei[EE + e]], 1);
}

__global__ __launch_bounds__(1024)
void scan_kernel(const int* __restrict__ hist, int* __restrict__ rowptr,
                 int* __restrict__ rowcur){
    const int br = blockIdx.x;
    hist   += br*NN;
    rowptr += br*(NN+1);
    rowcur += br*(NN+1);
    __shared__ int sums[1024];
    const int t = threadIdx.x;
    const int base = t*16;
    int loc[16]; int s = 0;
    #pragma unroll
    for (int i=0;i<16;i++){ loc[i]=s; s += hist[base+i]; }
    sums[t] = s; __syncthreads();
    for (int o=1;o<1024;o<<=1){
        int v = (t>=o) ? sums[t-o] : 0;
        __syncthreads();
        sums[t] += v;
        __syncthreads();
    }
    int pref = (t>0) ? sums[t-1] : 0;
    #pragma unroll
    for (int i=0;i<16;i++){
        int v = pref + loc[i];
        rowptr[base+i] = v;
        rowcur[base+i] = v;
    }
    if (t==1023) rowptr[NN] = sums[1023];
}

__global__ void scatter_kernel(const int* __restrict__ ei1, const int* __restrict__ ei2,
                               int* __restrict__ rowcur, int* __restrict__ srcs){
    int eg = blockIdx.x*256 + threadIdx.x;
    int br = eg >> 16, e = eg & (EE-1);
    const int* ei = br ? ei2 : ei1;
    int d = ei[EE + e];
    int pos = atomicAdd(&rowcur[br*(NN+1) + d], 1);
    srcs[br*EE + pos] = ei[e];
}

// ======= attention layer-1: s bf16 [2NN,256], q/k/v fp8 [2NN,768], H=2, D=128 =========
__global__ __launch_bounds__(256)
void attn128_f8(const bf16* __restrict__ s1, const unsigned char* __restrict__ f81,
                bf16* __restrict__ hout,
                const int* __restrict__ rowptr, const int* __restrict__ srcs)
{
    const int lane = threadIdx.x & 63;
    const int gw = blockIdx.x * 4 + (threadIdx.x >> 6);
    const int n = gw >> 1;               // global node 0..2NN
    const int h = gw & 1;
    int br = n >> 14;
    int brNN = br*NN, nl = n - brNN;
    rowptr += br*(NN+1); srcs += br*EE;
    const float qscale = rsqrtf(128.f) * 1.44269504f;
    const int hd = h*128 + lane*2;

    unsigned short qw; __builtin_memcpy(&qw, f81 + (size_t)n*768 + hd, 2);
    floatx2 qd = __builtin_amdgcn_cvt_pk_f32_fp8((int)qw, false);
    float qr[2] = { qd[0]*qscale, qd[1]*qscale };

    const int e0 = rowptr[nl], e1 = rowptr[nl+1];
    float m = -INFINITY, z = 0.f;
    float acc[2] = {0.f, 0.f};

    for (int base = e0; base < e1; base += 4){
        const int cnt = min(4, e1 - base);
        int sl = srcs[min(base + (lane & 3), e1 - 1)];
        int src[4];
        #pragma unroll
        for (int j=0;j<4;j++) src[j] = __shfl(sl, j, 64);

        unsigned short kw[4], vw[4];
        #pragma unroll
        for (int j=0;j<4;j++){
            if (j < cnt){
                const unsigned char* rp = f81 + (size_t)(brNN + src[j])*768;
                __builtin_memcpy(&kw[j], rp + 256 + hd, 2);
                __builtin_memcpy(&vw[j], rp + 512 + hd, 2);
            }
        }
        float dt[4];
        #pragma unroll
        for (int j=0;j<4;j++){
            float d = 0.f;
            if (j < cnt){
                floatx2 kd = __builtin_amdgcn_cvt_pk_f32_fp8((int)kw[j], false);
                d = qr[0]*kd[0] + qr[1]*kd[1];
            }
            dt[j] = d;
        }
        #pragma unroll
        for (int o=32;o;o>>=1){
            #pragma unroll
            for (int j=0;j<4;j++) dt[j] += __shfl_xor(dt[j], o, 64);
        }
        float cm = -INFINITY;
        #pragma unroll
        for (int j=0;j<4;j++) if (j < cnt) cm = fmaxf(cm, dt[j]);
        const float mn = fmaxf(m, cm);
        const float cs = exp2f(m - mn);
        z *= cs;
        acc[0] *= cs; acc[1] *= cs;
        #pragma unroll
        for (int j=0;j<4;j++){
            if (j < cnt){
                const float w = exp2f(dt[j] - mn);
                z += w;
                floatx2 vd = __builtin_amdgcn_cvt_pk_f32_fp8((int)vw[j], false);
                acc[0] += w*vd[0];
                acc[1] += w*vd[1];
            }
        }
        m = mn;
    }
    const float invz = 1.0f/(z + 1e-16f);
    const short2v sv = *(const short2v*)(s1 + (size_t)n*256 + hd);
    short2v ov;
    ov[0] = f2b(lrelu_f(b2f(sv[0]) + acc[0]*invz));
    ov[1] = f2b(lrelu_f(b2f(sv[1]) + acc[1]*invz));
    *(short2v*)(hout + (size_t)n*256 + hd) = ov;
}

// ====== attention layer-2 (stacked branches) + fused segment-max pool ================
// s bf16 [2NN,512]; q/k/v fp8 [2NN,1536] (q 0-511, k 512-1023, v 1024-1535).
__global__ __launch_bounds__(256)
void attn512_f8(const bf16* __restrict__ s2, const unsigned char* __restrict__ f82,
                const int* __restrict__ rowptr, const int* __restrict__ srcs,
                const int* __restrict__ bt1, const int* __restrict__ bt2,
                unsigned int* __restrict__ gkey, int gc0)
{
    __shared__ float Sh[4][512];
    __shared__ int Sgid[4];
    const int lane = threadIdx.x & 63;
    const int wave = threadIdx.x >> 6;
    const int n = blockIdx.x * 4 + wave;     // global node 0..2NN (block never spans br)
    const int br = n >> 14;
    const int brNN = br*NN, nl = n - brNN;
    const int* rp_ = rowptr + br*(NN+1);
    const int* sp_ = srcs + br*EE;
    const float qscale = rsqrtf(512.f) * 1.44269504f;
    const int hd = lane*8;

    float qr[8];
    {
        const uint2v qv = *(const uint2v*)(f82 + (size_t)n*1536 + hd);
        floatx2 a = __builtin_amdgcn_cvt_pk_f32_fp8((int)qv[0], false);
        floatx2 b = __builtin_amdgcn_cvt_pk_f32_fp8((int)qv[0], true);
        floatx2 c = __builtin_amdgcn_cvt_pk_f32_fp8((int)qv[1], false);
        floatx2 d = __builtin_amdgcn_cvt_pk_f32_fp8((int)qv[1], true);
        qr[0]=a[0]*qscale; qr[1]=a[1]*qscale; qr[2]=b[0]*qscale; qr[3]=b[1]*qscale;
        qr[4]=c[0]*qscale; qr[5]=c[1]*qscale; qr[6]=d[0]*qscale; qr[7]=d[1]*qscale;
    }

    const int e0 = rp_[nl], e1 = rp_[nl+1];
    float m = -INFINITY, z = 0.f;
    float acc[8];
    #pragma unroll
    for (int i=0;i<8;i++) acc[i] = 0.f;

    for (int base = e0; base < e1; base += 4){
        const int cnt = min(4, e1 - base);
        int sl = sp_[min(base + (lane & 3), e1 - 1)];
        int src[4];
        #pragma unroll
        for (int j=0;j<4;j++) src[j] = __shfl(sl, j, 64);

        uint2v k2[4], v2[4];
        #pragma unroll
        for (int j=0;j<4;j++){
            if (j < cnt){
                const unsigned char* rp = f82 + (size_t)(brNN + src[j])*1536;
                k2[j] = *(const uint2v*)(rp + 512 + hd);
                v2[j] = *(const uint2v*)(rp + 1024 + hd);
            }
        }
        float dt[4];
        #pragma unroll
        for (int j=0;j<4;j++){
            float d = 0.f;
            if (j < cnt){
                floatx2 p0 = __builtin_amdgcn_cvt_pk_f32_fp8((int)k2[j][0], false);
                floatx2 p1 = __builtin_amdgcn_cvt_pk_f32_fp8((int)k2[j][0], true);
                floatx2 p2 = __builtin_amdgcn_cvt_pk_f32_fp8((int)k2[j][1], false);
                floatx2 p3 = __builtin_amdgcn_cvt_pk_f32_fp8((int)k2[j][1], true);
                d = qr[0]*p0[0] + qr[1]*p0[1] + qr[2]*p1[0] + qr[3]*p1[1]
                  + qr[4]*p2[0] + qr[5]*p2[1] + qr[6]*p3[0] + qr[7]*p3[1];
            }
            dt[j] = d;
        }
        #pragma unroll
        for (int o=32;o;o>>=1){
            #pragma unroll
            for (int j=0;j<4;j++) dt[j] += __shfl_xor(dt[j], o, 64);
        }
        float cm = -INFINITY;
        #pragma unroll
        for (int j=0;j<4;j++) if (j < cnt) cm = fmaxf(cm, dt[j]);
        const float mn = fmaxf(m, cm);
        const float cs = exp2f(m - mn);
        z *= cs;
        #pragma unroll
        for (int i=0;i<8;i++) acc[i] *= cs;
        #pragma unroll
        for (int j=0;j<4;j++){
            if (j < cnt){
                const float w = exp2f(dt[j] - mn);
                z += w;
                floatx2 p0 = __builtin_amdgcn_cvt_pk_f32_fp8((int)v2[j][0], false);
                floatx2 p1 = __builtin_amdgcn_cvt_pk_f32_fp8((int)v2[j][0], true);
                floatx2 p2 = __builtin_amdgcn_cvt_pk_f32_fp8((int)v2[j][1], false);
                floatx2 p3 = __builtin_amdgcn_cvt_pk_f32_fp8((int)v2[j][1], true);
                acc[0] += w*p0[0]; acc[1] += w*p0[1]; acc[2] += w*p1[0]; acc[3] += w*p1[1];
                acc[4] += w*p2[0]; acc[5] += w*p2[1]; acc[6] += w*p3[0]; acc[7] += w*p3[1];
            }
        }
        m = mn;
    }
    const float invz = 1.0f/(z + 1e-16f);
    const short8 sv = *(const short8*)(s2 + (size_t)n*512 + hd);
    #pragma unroll
    for (int i=0;i<8;i++) Sh[wave][hd + i] = lrelu_f(b2f(sv[i]) + acc[i]*invz);
    if (lane == 0) Sgid[wave] = br*BB + (br ? bt2[nl] : bt1[nl]);
    __syncthreads();

    // segmented max over the block's 4 rows, one atomic per (graph,col) run
    #pragma unroll
    for (int cc=0; cc<2; cc++){
        const int col = threadIdx.x*2 + cc;
        float mx = Sh[0][col];
        int gid = Sgid[0];
        #pragma unroll
        for (int r=1; r<4; r++){
            if (Sgid[r] == gid) mx = fmaxf(mx, Sh[r][col]);
            else {
                atomicMax(&gkey[(size_t)gid*1024 + gc0 + col], fkey(mx));
                gid = Sgid[r]; mx = Sh[r][col];
            }
        }
        atomicMax(&gkey[(size_t)gid*1024 + gc0 + col], fkey(mx));
    }
}

// ================= tail dense layer via MFMA (1024 threads = 16 waves) ===============
// K is COMPILE-TIME: KS constexpr, ks-loop fully unrolled, with an explicit 8-deep
// circular B-prefetch (statically indexed -> stays in VGPRs, rule #20).
// lda/ldc are PADDED strides (+4 floats) -> bank-conflict-free (R3, verified 512 cnt).
template<int R, int N, int K, int ACT>
__device__ __forceinline__ void dense_mfma(
    const bf16* __restrict__ Wm, const float* __restrict__ bias,
    const float* __restrict__ gam, const float* __restrict__ bet, float bns,
    const float* A, int lda, float* C, int ldc, int tid)
{
    constexpr int T   = N / 16;
    constexpr int TPW = (T + 15) / 16;
    constexpr int KS  = ((K + 31) & ~31) >> 5;
    constexpr int PF  = (KS < 8) ? KS : 8;       // B-prefetch depth (ks-steps)
    const int wave = tid >> 6;
    const int lane = tid & 63;
    const int am = lane & 15;
    const int ak = (lane >> 4) * 8;

    floatx4 acc[TPW];
    #pragma unroll
    for (int tp=0; tp<TPW; tp++) acc[tp] = (floatx4){0.f,0.f,0.f,0.f};

    short8 bb[PF][TPW];
    #pragma unroll
    for (int p=0; p<PF; p++){
        #pragma unroll
        for (int tp=0; tp<TPW; tp++){
            const int tile = wave + tp*16;
            if (tile < T)
                bb[p][tp] = *(const short8*)(Wm + ((size_t)(tile*KS + p))*512 + lane*8);
        }
    }

    #pragma unroll
    for (int ks = 0; ks < KS; ks++){
        short8 af = (short8){0,0,0,0,0,0,0,0};
        if (am < R){
            const float* ap = A + am*lda + ks*32 + ak;
            const floatx4 a0 = *(const floatx4*)ap;
            const floatx4 a1 = *(const floatx4*)(ap + 4);
            af[0]=f2b(a0[0]); af[1]=f2b(a0[1]); af[2]=f2b(a0[2]); af[3]=f2b(a0[3]);
            af[4]=f2b(a1[0]); af[5]=f2b(a1[1]); af[6]=f2b(a1[2]); af[7]=f2b(a1[3]);
        }
        #pragma unroll
        for (int tp=0; tp<TPW; tp++){
            const int tile = wave + tp*16;
            if (tile < T)
                acc[tp] = __builtin_amdgcn_mfma_f32_16x16x32_bf16(af, bb[ks % PF][tp], acc[tp], 0,0,0);
        }
        if (ks + PF < KS){
            #pragma unroll
            for (int tp=0; tp<TPW; tp++){
                const int tile = wave + tp*16;
                if (tile < T)
                    bb[ks % PF][tp] = *(const short8*)(Wm + ((size_t)(tile*KS + ks + PF))*512 + lane*8);
            }
        }
    }
    const int crow = (lane >> 4) * 4;
    const int ccol = lane & 15;
    #pragma unroll
    for (int tp=0; tp<TPW; tp++){
        const int tile = wave + tp*16;
        if (tile < T){
            #pragma unroll
            for (int r=0; r<4; r++){
                const int row = crow + r;
                if (row < R){
                    const int n = tile*16 + ccol;
                    float v = acc[tp][r] + bias[n];
                    if (ACT==1) v = lrelu_f(v);
                    if (ACT==2) v = lrelu_f(v*bns*gam[n] + bet[n]);
                    C[row*ldc + n] = v;
                }
            }
        }
    }
    __syncthreads();
}

// ================= fused tail: graph-head + cell branch + head MLP, 2 graphs/block ====
// All activation buffers padded +4 floats/row (16B) -> bank-conflict-free dense_mfma.
__global__ __launch_bounds__(1024)
void tail_kernel(const unsigned int* __restrict__ gkey,  // [2*BB][1024] encoded maxes
                 const float* __restrict__ cell,         // [BB][954]
                 const bf16*  __restrict__ Wtp,          // packed tail weights
                 const float* __restrict__ bg1, const float* __restrict__ bg2,
                 const float* __restrict__ br1, const float* __restrict__ br2,
                 const float* __restrict__ br3,
                 const float* __restrict__ bf1,
                 const float* __restrict__ gbn1, const float* __restrict__ bbn1,
                 const float* __restrict__ bf2,
                 const float* __restrict__ gbn2, const float* __restrict__ bbn2,
                 const float* __restrict__ wf3, const float* __restrict__ bf3,
                 float bns, float* __restrict__ outp)
{
    __shared__ float Sg[4][1028];    // rows: lg*2 + br   (pad +4)
    __shared__ float Sgh[4][516];
    __shared__ float Sgout[4][132];
    __shared__ float Scell[2][964];
    __shared__ float Sc1[2][516];
    __shared__ float Sc2[2][260];
    __shared__ float Sc3[2][132];
    __shared__ float Sxc[2][388];
    __shared__ float Sf1[2][516];
    __shared__ float Sf2[2][260];
    __shared__ float inv4[4], invc[2], invx[2];

    const int tid = threadIdx.x;
    const int wv  = tid >> 6;
    const int ln  = tid & 63;
    const int b0  = blockIdx.x * 2;

    {
        int idx = tid*4;                 // 0..4092
        int r = idx >> 10, c = idx & 1023;
        int lg = r >> 1, br = r & 1;
        const unsigned int* gp = gkey + (size_t)(br*BB + b0 + lg)*1024 + c;
        #pragma unroll
        for (int i=0;i<4;i++) Sg[r][c+i] = fdec(gp[i]);
    }
    for (int idx = tid; idx < 2*954; idx += 1024){
        int r = (idx >= 954) ? 1 : 0;
        int c = idx - r*954;
        Scell[r][c] = cell[(size_t)(b0 + r)*954 + c];
    }
    if (tid < 12){ int r = tid/6; Scell[r][954 + tid%6] = 0.f; }
    __syncthreads();

    if (wv < 2){
        float s = 0.f;
        for (int c = ln; c < 954; c += 64){ float v = Scell[wv][c]; s += v*v; }
        #pragma unroll
        for (int o=32;o;o>>=1) s += __shfl_xor(s, o, 64);
        if (ln == 0) invc[wv] = 1.0f / fmaxf(sqrtf(s), 1e-12f);
    }
    __syncthreads();
    #pragma unroll
    for (int r=0;r<2;r++)
        for (int c = tid; c < 954; c += 1024) Scell[r][c] *= invc[r];
    __syncthreads();

    dense_mfma<4,512,1024,1>(Wtp+OG1, bg1, nullptr, nullptr, 1.f, &Sg[0][0],   1028, &Sgh[0][0],  516, tid);
    dense_mfma<4,128,512,0>(Wtp+OG2, bg2, nullptr, nullptr, 1.f, &Sgh[0][0],  516,  &Sgout[0][0],132, tid);
    dense_mfma<2,512,954,1>(Wtp+OR1, br1, nullptr, nullptr, 1.f, &Scell[0][0], 964, &Sc1[0][0],  516, tid);
    dense_mfma<2,256,512,1>(Wtp+OR2, br2, nullptr, nullptr, 1.f, &Sc1[0][0],   516, &Sc2[0][0],  260, tid);
    dense_mfma<2,128,256,0>(Wtp+OR3, br3, nullptr, nullptr, 1.f, &Sc2[0][0],   260, &Sc3[0][0],  132, tid);

    if (wv < 4){
        float a = Sgout[wv][ln], bq = Sgout[wv][ln+64];
        float s = a*a + bq*bq;
        #pragma unroll
        for (int o=32;o;o>>=1) s += __shfl_xor(s, o, 64);
        if (ln == 0) inv4[wv] = 1.0f / fmaxf(sqrtf(s), 1e-12f);
    }
    __syncthreads();

    if (tid < 768){
        int lg = tid / 384, j = tid - lg*384;
        float v;
        if (j < 128)      v = Sgout[lg*2+0][j]     * inv4[lg*2+0];
        else if (j < 256) v = Sgout[lg*2+1][j-128] * inv4[lg*2+1];
        else              v = Sc3[lg][j-256];
        Sxc[lg][j] = v;
    }
    __syncthreads();
    if (wv < 2){
        float s = 0.f;
        #pragma unroll
        for (int i=0;i<6;i++){ float v = Sxc[wv][ln + i*64]; s += v*v; }
        #pragma unroll
        for (int o=32;o;o>>=1) s += __shfl_xor(s, o, 64);
        if (ln == 0) invx[wv] = 1.0f / fmaxf(sqrtf(s), 1e-12f);
    }
    __syncthreads();
    if (tid < 768){
        int lg = tid / 384, j = tid - lg*384;
        Sxc[lg][j] *= invx[lg];
    }
    __syncthreads();

    dense_mfma<2,512,384,2>(Wtp+OF1, bf1, gbn1, bbn1, bns, &Sxc[0][0], 388, &Sf1[0][0], 516, tid);
    dense_mfma<2,256,512,2>(Wtp+OF2, bf2, gbn2, bbn2, bns, &Sf1[0][0], 516, &Sf2[0][0], 260, tid);

    if (wv < 2){
        float s = 0.f;
        #pragma unroll
        for (int i=0;i<4;i++){ int c = ln + i*64; s += Sf2[wv][c]*wf3[c]; }
        #pragma unroll
        for (int o=32;o;o>>=1) s += __shfl_xor(s, o, 64);
        if (ln == 0) outp[b0 + wv] = 1.0f/(1.0f + expf(-(s + bf3[0])));
    }
}

extern "C" void kernel_launch(void* const* d_in, const int* in_sizes, int n_in,
                              void* d_out, int out_size, void* d_ws, size_t ws_size,
                              hipStream_t stream)
{
    const float* x1  = (const float*)d_in[0];
    const int*   ei1 = (const int*)  d_in[1];
    const int*   bt1 = (const int*)  d_in[2];
    const float* x2  = (const float*)d_in[3];
    const int*   ei2 = (const int*)  d_in[4];
    const int*   bt2 = (const int*)  d_in[5];
    const float* cell= (const float*)d_in[6];
    const float* wq1=(const float*)d_in[7];  const float* bq1=(const float*)d_in[8];
    const float* wk1=(const float*)d_in[9];  const float* bk1=(const float*)d_in[10];
    const float* wv1=(const float*)d_in[11]; const float* bv1=(const float*)d_in[12];
    const float* ws1=(const float*)d_in[13]; const float* bs1=(const float*)d_in[14];
    const float* wq2=(const float*)d_in[15]; const float* bq2=(const float*)d_in[16];
    const float* wk2=(const float*)d_in[17]; const float* bk2=(const float*)d_in[18];
    const float* wv2=(const float*)d_in[19]; const float* bv2=(const float*)d_in[20];
    const float* ws2=(const float*)d_in[21]; const float* bs2q=(const float*)d_in[22];
    const float* wg1=(const float*)d_in[23]; const float* bg1=(const float*)d_in[24];
    const float* wg2=(const float*)d_in[25]; const float* bg2=(const float*)d_in[26];
    const float* wr1=(const float*)d_in[27]; const float* br1=(const float*)d_in[28];
    const float* wr2=(const float*)d_in[29]; const float* br2=(const float*)d_in[30];
    const float* wr3=(const float*)d_in[31]; const float* br3=(const float*)d_in[32];
    const float* wf1=(const float*)d_in[33]; const float* bf1=(const float*)d_in[34];
    const float* gbn1=(const float*)d_in[35];const float* bbn1=(const float*)d_in[36];
    const float* wf2=(const float*)d_in[37]; const float* bf2=(const float*)d_in[38];
    const float* gbn2=(const float*)d_in[39];const float* bbn2=(const float*)d_in[40];
    const float* wf3=(const float*)d_in[41]; const float* bf3=(const float*)d_in[42];
    float* outp = (float*)d_out;
    (void)in_sizes; (void)n_in; (void)out_size; (void)ws_size;

    const float BNS = 1.0f / sqrtf(1.0f + 1e-5f);

    // ---- workspace arena (~107 MB peak; BIG region phase-aliased) ----
    char* basep = (char*)d_ws;
    size_t off = 0;
    auto alloc = [&](size_t nbytes)->char* {
        char* p = basep + off;
        off += (nbytes + 255) & ~(size_t)255;
        return p;
    };
    int* rowptr2  = (int*)  alloc((size_t)2*(NN+1)*4);
    int* rowcur2  = (int*)  alloc((size_t)2*(NN+1)*4);
    int* cnt2     = (int*)  alloc((size_t)2*NN*4);
    int* srcs2    = (int*)  alloc((size_t)2*EE*4);
    unsigned int* gkey = (unsigned int*)alloc((size_t)2*BB*1024*4);  // pooled-max keys
    float* b1c    = (float*)alloc((size_t)1024*4);
    float* b2c    = (float*)alloc((size_t)4096*4);
    bf16* W1t     = (bf16*) alloc((size_t)1024*96*2);
    bf16* W2t     = (bf16*) alloc((size_t)2*2048*256*2);
    bf16* Wtp     = (bf16*) alloc((size_t)TAILW_TOTAL*2);
    bf16* h1      = (bf16*) alloc((size_t)2*NN*256*2);    // layer-1 out, both branches
    // BIG phase-aliased region (80 MB):
    //   phase1: xa [2NN,96] bf16 (6.3MB) | s1 [2NN,256] bf16 (16MB) | f81 [2NN,768] u8 (24MB)
    //   phase2: s2 [2NN,512] bf16 (32MB) | f82 [2NN,1536] u8 (48MB)
    char* BIG     = alloc((size_t)2*NN*512*2 + (size_t)2*NN*1536);
    bf16* xa      = (bf16*)BIG;
    bf16* s1a     = (bf16*)(BIG + 6291456);
    unsigned char* f81 = (unsigned char*)(BIG + 6291456 + 16777216);
    bf16* s2a     = (bf16*)BIG;
    unsigned char* f82 = (unsigned char*)(BIG + (size_t)2*NN*512*2);

    // ---- prep (1 mega dispatch) + CSR ----
    (void)hipMemsetAsync(cnt2, 0, (size_t)2*NN*4, stream);
    prep_mega_kernel<<<P_GK/256,256,0,stream>>>(
        wq1,wk1,wv1,ws1, bq1,bk1,bv1,bs1,
        wq2,wk2,wv2,ws2, bq2,bk2,bv2,bs2q,
        wg1,wg2,wr1,wr2,wr3,wf1,wf2,
        x1,x2,
        W1t,b1c,W2t,b2c, Wtp, xa, gkey);
    hist_kernel<<<2*EE/256,256,0,stream>>>(ei1, ei2, cnt2);
    scan_kernel<<<2,1024,0,stream>>>(cnt2, rowptr2, rowcur2);
    scatter_kernel<<<2*EE/256,256,0,stream>>>(ei1, ei2, rowcur2, srcs2);

    // ---- layer 1 (both branches stacked): [2NN,96]x[96,1024], s bf16 / q,k,v fp8 ----
    mfma_gemm<3><<<dim3(2*NN/128, 8),256,0,stream>>>(xa,96, W1t, b1c,
                                                     s1a,256, f81,768, 256);
    attn128_f8<<<2*NN*2/4,256,0,stream>>>(s1a, f81, h1, rowptr2, srcs2);

    // ---- layer 2 (branches stacked): per head GEMM + attn+pool fused ----
    for (int h=0; h<2; h++){
        mfma_gemm<8><<<dim3(2*NN/128, 16),256,0,stream>>>(
            h1, 256, W2t + (size_t)h*524288,
            b2c + h*2048, s2a,512, f82,1536, 512);
        attn512_f8<<<2*NN/4,256,0,stream>>>(s2a, f82, rowptr2, srcs2, bt1, bt2,
                                            gkey, h*512);
    }

    // ---- fused tail: graph-head + cell + head MLP + sigmoid, one dispatch ----
    tail_kernel<<<BB/2,1024,0,stream>>>(gkey, cell, Wtp,
                                        bg1,bg2, br1,br2,br3,
                                        bf1,gbn1,bbn1, bf2,gbn2,bbn2, wf3,bf3,
                                        BNS, outp);
}